// Round 3
// baseline (824.693 us; speedup 1.0000x reference)
//
#include <hip/hip_runtime.h>

// ATTNRNNAgent: B=4096, N=64, E=128, A=32, nh=8, e=32, HID=256, ATT=256, N_ACT=32
// K0 (weights->bf16, mask dtype detect) -> 2x( k1_fqkv , k2_attn ) -> k3_gru -> k4_out
// All GEMMs via v_mfma_f32_16x16x32_bf16
//   A-frag: row=lane&15, k=(lane>>4)*8+i ; B-frag: col=lane&15 same k
//   D-frag: col=lane&15, row=(lane>>4)*4+r

using bfrag = __attribute__((ext_vector_type(8))) short;   // 8 bf16
using ffrag = __attribute__((ext_vector_type(4))) float;   // 4 f32 acc

#define MFMA(a,b,c) __builtin_amdgcn_mfma_f32_16x16x32_bf16((a),(b),(c),0,0,0)
// XOR swizzle for row-major bf16 LDS tiles (16B granular)
#define SWZ(row,col,S,xm) ((row)*(S) + ((((col)&~7) ^ (((row)&(xm))<<3)) | ((col)&7)))

// ws layout (in shorts)
#define OFF_FC1  128L
#define OFF_QW   32896L
#define OFF_KW   98432L
#define OFF_VW   163968L
#define OFF_WIH  229504L
#define OFF_WHH  426112L
#define OFF_OW   622720L
#define OFF_QFULL 630912L          // full-batch q (bf16), 33554432 shorts
#define OFF_ATTB 34185344L
#define WS_NEED_BYTES 135479552L

__device__ inline unsigned short f2bf(float x){
  union { float f; unsigned u; } v; v.f = x;
  unsigned r = v.u + 0x7fffu + ((v.u >> 16) & 1u);   // RNE
  return (unsigned short)(r >> 16);
}
__device__ inline bool getmask(const void* p, long i, int byteflag){
  return byteflag ? (((const unsigned char*)p)[i] != 0)
                  : (((const int*)p)[i] != 0);
}
__device__ inline ffrag fzero(){ ffrag z; z[0]=0.f; z[1]=0.f; z[2]=0.f; z[3]=0.f; return z; }

// ---------------- K0: weights -> bf16, detect mask dtype ----------------
__global__ void k0_prep(const float* __restrict__ fc1, const float* __restrict__ qw,
    const float* __restrict__ kw, const float* __restrict__ vw, const float* __restrict__ wih,
    const float* __restrict__ whh, const float* __restrict__ ow,
    const void* __restrict__ obsm, short* __restrict__ ws){
  long tid = (long)blockIdx.x*blockDim.x + threadIdx.x;
  long n = (long)gridDim.x*blockDim.x;
  if (tid == 0){
    const int* mi = (const int*)obsm;
    int f = 0;
    for (int i=0;i<256;i++){ if ((unsigned)mi[i] > 1u){ f = 1; break; } }
    ((int*)ws)[0] = f;
  }
  for (long i=tid; i<32768; i+=n) ws[OFF_FC1+i] = (short)f2bf(fc1[i]);
  for (long i=tid; i<65536; i+=n){
    ws[OFF_QW+i] = (short)f2bf(qw[i]);
    ws[OFF_KW+i] = (short)f2bf(kw[i]);
    ws[OFF_VW+i] = (short)f2bf(vw[i]);
  }
  for (long i=tid; i<196608; i+=n){
    ws[OFF_WIH+i] = (short)f2bf(wih[i]);
    ws[OFF_WHH+i] = (short)f2bf(whh[i]);
  }
  for (long i=tid; i<8192; i+=n) ws[OFF_OW+i] = (short)f2bf(ow[i]);
}

// ---------------- K1: fused fc1 + QKV projection (per 131072-row chunk) ----------------
// phase1: x = relu(inp@fc1^T+b) for 128 rows -> regs -> x_s (LDS) -> A-frags
// phase2: 12 pipelined 64-col segments: out = x @ W_seg^T + bias
__global__ __launch_bounds__(512) void k1_fqkv(const float* __restrict__ inp,
    const short* __restrict__ fc1B, const float* __restrict__ fc1_b,
    const short* __restrict__ wq, const short* __restrict__ wk, const short* __restrict__ wv,
    const float* __restrict__ qb, const float* __restrict__ kb, const float* __restrict__ vb,
    short* __restrict__ qF, short* __restrict__ kC, short* __restrict__ vC, int chunkB){
  __shared__ __align__(16) short smem[65536];   // 128 KB
  short* a_s  = smem;            // phase1 A: 128x128 (32 KB)
  short* fw_s = smem + 16384;    // phase1 W: 256x128 (64 KB)
  short* x_s  = smem;            // phase2 X: 128x256 (64 KB)
  // phase2 weight ping-pong: smem+32768 (buf0), smem+49152 (buf1), 32 KB each
  int t = threadIdx.x;
  long R0 = (long)blockIdx.x * 128;            // chunk-local row base
  long grow0 = (long)chunkB*131072 + R0;       // global input row base
  int lane = t&63, w = t>>6, lr = lane&15, ko = lane>>4;
  // ---- phase1 staging ----
  for (int i=0;i<4;i++){
    int c = t + i*512; int row = c>>4; int cc = (c&15)*8;
    const float* src = inp + (grow0 + row)*128 + cc;
    float4 f0 = *(const float4*)src; float4 f1 = *(const float4*)(src+4);
    bfrag v8;
    v8[0]=(short)f2bf(f0.x); v8[1]=(short)f2bf(f0.y); v8[2]=(short)f2bf(f0.z); v8[3]=(short)f2bf(f0.w);
    v8[4]=(short)f2bf(f1.x); v8[5]=(short)f2bf(f1.y); v8[6]=(short)f2bf(f1.z); v8[7]=(short)f2bf(f1.w);
    *(bfrag*)(a_s + SWZ(row, cc, 128, 7)) = v8;
  }
  for (int i=0;i<8;i++){
    int c = t + i*512; int row = c>>4; int cc = (c&15)*8;
    *(bfrag*)(fw_s + SWZ(row, cc, 128, 7)) = *(const bfrag*)(fc1B + row*128 + cc);
  }
  __syncthreads();
  // ---- phase1 MFMA: x-tile (128x256) ----
  ffrag acc1[16];
  #pragma unroll
  for (int i=0;i<16;i++) acc1[i]=fzero();
  for (int ks=0; ks<4; ks++){
    int kc = ks*32 + ko*8;
    bfrag a = *(const bfrag*)(a_s + SWZ(w*16+lr, kc, 128, 7));
    #pragma unroll
    for (int nt=0; nt<16; nt++){
      bfrag bb = *(const bfrag*)(fw_s + SWZ(nt*16+lr, kc, 128, 7));
      acc1[nt] = MFMA(a, bb, acc1[nt]);
    }
  }
  __syncthreads();   // all phase1 LDS reads complete -> reuse smem
  // write x (bias+relu, bf16) into x_s (wave writes only its own 16 rows)
  #pragma unroll
  for (int nt=0; nt<16; nt++){
    float bias = fc1_b[nt*16+lr];
    #pragma unroll
    for (int r=0;r<4;r++){
      int row = w*16 + ko*4 + r;
      float v = acc1[nt][r] + bias; v = v>0.f?v:0.f;
      x_s[SWZ(row, nt*16+lr, 256, 7)] = (short)f2bf(v);
    }
  }
  // preload own A-frags (wave-private rows -> no barrier needed)
  bfrag a_r[8];
  #pragma unroll
  for (int ks=0; ks<8; ks++)
    a_r[ks] = *(const bfrag*)(x_s + SWZ(w*16+lr, ks*32+ko*8, 256, 7));
  // ---- phase2: 12 pipelined segments of 64 cols ----
  auto STAGE2 = [&](int s){
    int kind = s>>2; int rb = (s&3)*64;
    const short* wsrc = (kind==0?wq:(kind==1?wk:wv)) + (long)rb*256;
    short* dst = smem + 32768 + (s&1)*16384;
    #pragma unroll
    for (int i=0;i<4;i++){
      int c = t + i*512; int row = c>>5; int cc = (c&31)*8;
      *(bfrag*)(dst + SWZ(row, cc, 256, 7)) = *(const bfrag*)(wsrc + (long)row*256 + cc);
    }
  };
  STAGE2(0);
  __syncthreads();
  for (int s=0; s<12; s++){
    if (s < 11) STAGE2(s+1);
    const short* wcur = smem + 32768 + (s&1)*16384;
    ffrag acc2[4];
    #pragma unroll
    for (int i=0;i<4;i++) acc2[i]=fzero();
    #pragma unroll
    for (int ks=0; ks<8; ks++){
      int kc = ks*32 + ko*8;
      #pragma unroll
      for (int nt=0; nt<4; nt++){
        bfrag bb = *(const bfrag*)(wcur + SWZ(nt*16+lr, kc, 256, 7));
        acc2[nt] = MFMA(a_r[ks], bb, acc2[nt]);
      }
    }
    int kind = s>>2; int rb = (s&3)*64;
    const float* bsrc = (kind==0?qb:(kind==1?kb:vb));
    #pragma unroll
    for (int nt=0; nt<4; nt++){
      int colk = rb + nt*16 + lr;
      float bias = bsrc[colk];
      #pragma unroll
      for (int r=0;r<4;r++){
        int row = w*16 + ko*4 + r;
        float v = acc2[nt][r] + bias;
        if (kind==0){
          if ((row&32)==0){                       // q: only agent rows n<32
            long grow = grow0 + row;
            long qrow = ((grow>>6)<<5) + (grow&31);
            qF[qrow*256 + colk] = (short)f2bf(v);
          }
        } else if (kind==1){
          kC[(R0+row)*256 + colk] = (short)f2bf(v);
        } else {
          v = v>0.f?v:0.f;
          vC[(R0+row)*256 + colk] = (short)f2bf(v);
        }
      }
    }
    __syncthreads();
  }
}

// ---------------- K2: attention, one wave per (b,head) ----------------
__global__ __launch_bounds__(512,4) void k2_attn(const short* __restrict__ qF,
    const short* __restrict__ kC, const short* __restrict__ vC,
    const void* __restrict__ obsm, short* __restrict__ attB,
    const int* __restrict__ flagp, int chunkB){
  __shared__ __align__(16) short vT_s[8][2048];   // per-wave v^T [e=32][n=64]
  __shared__ __align__(16) short p_s[8][2048];    // per-wave p   [a=32][n=64]
  __shared__ unsigned char m_s[2048];             // obs_mask rows 0..31
  int t = threadIdx.x, bl = blockIdx.x;
  long b = (long)chunkB*2048 + bl;
  int lane = t&63, w = t>>6, lr = lane&15, ko = lane>>4;
  int mflag = *flagp;
  if (mflag){
    uchar4 mv = *(const uchar4*)((const unsigned char*)obsm + b*4096 + t*4);
    m_s[t*4]=mv.x; m_s[t*4+1]=mv.y; m_s[t*4+2]=mv.z; m_s[t*4+3]=mv.w;
  } else {
    int4 mv = *(const int4*)((const int*)obsm + b*4096 + t*4);
    m_s[t*4]  =(unsigned char)(mv.x!=0); m_s[t*4+1]=(unsigned char)(mv.y!=0);
    m_s[t*4+2]=(unsigned char)(mv.z!=0); m_s[t*4+3]=(unsigned char)(mv.w!=0);
  }
  const int h = w;
  const short* qh = qF + ((long)b*32)*256 + h*32 + ko*8;
  bfrag a_q[2];
  #pragma unroll
  for (int mt=0; mt<2; mt++) a_q[mt] = *(const bfrag*)(qh + (mt*16+lr)*256);
  const short* kh = kC + ((long)bl*64)*256 + h*32 + ko*8;
  bfrag b_k[4];
  #pragma unroll
  for (int nt=0; nt<4; nt++) b_k[nt] = *(const bfrag*)(kh + (nt*16+lr)*256);
  #pragma unroll
  for (int i=0;i<4;i++){
    int n = i*16 + (lane>>2); int e0 = (lane&3)*8;
    bfrag vv = *(const bfrag*)(vC + ((long)bl*64 + n)*256 + h*32 + e0);
    #pragma unroll
    for (int j=0;j<8;j++) vT_s[w][SWZ(e0+j, n, 64, 7)] = vv[j];
  }
  ffrag sc[2][4];
  #pragma unroll
  for (int mt=0; mt<2; mt++)
    #pragma unroll
    for (int nt=0; nt<4; nt++) sc[mt][nt] = MFMA(a_q[mt], b_k[nt], fzero());
  __syncthreads();   // m_s ready (vT/p are wave-private)
  const float scale = 0.17677669529663687f;   // 1/sqrt(32)
  float rsi[2][4];
  #pragma unroll
  for (int mt=0; mt<2; mt++){
    #pragma unroll
    for (int r=0; r<4; r++){
      int arow = mt*16 + ko*4 + r;
      float sv[4]; int mk[4];
      #pragma unroll
      for (int nt=0; nt<4; nt++){
        mk[nt] = m_s[arow*64 + nt*16 + lr];
        sv[nt] = sc[mt][nt][r] * scale;
      }
      float mx = -3.0e38f;
      #pragma unroll
      for (int nt=0; nt<4; nt++) if (!mk[nt]) mx = fmaxf(mx, sv[nt]);
      for (int d=1; d<16; d<<=1) mx = fmaxf(mx, __shfl_xor(mx, d));
      float sum = 0.f;
      #pragma unroll
      for (int nt=0; nt<4; nt++){
        float p = mk[nt] ? 0.f : __expf(sv[nt]-mx);
        sv[nt] = p; sum += p;
      }
      for (int d=1; d<16; d<<=1) sum += __shfl_xor(sum, d);
      rsi[mt][r] = sum > 0.f ? 1.f/sum : 0.f;   // all-masked row -> 0
      #pragma unroll
      for (int nt=0; nt<4; nt++)
        p_s[w][SWZ(arow, nt*16+lr, 64, 7)] = (short)f2bf(sv[nt]);
    }
  }
  ffrag o[2][2];
  #pragma unroll
  for (int mt=0;mt<2;mt++)
    #pragma unroll
    for (int nt=0;nt<2;nt++) o[mt][nt]=fzero();
  #pragma unroll
  for (int kk=0; kk<2; kk++){
    int kc = kk*32 + ko*8;
    bfrag pa0 = *(const bfrag*)(p_s[w]  + SWZ(lr,    kc, 64, 7));
    bfrag pa1 = *(const bfrag*)(p_s[w]  + SWZ(16+lr, kc, 64, 7));
    bfrag bv0 = *(const bfrag*)(vT_s[w] + SWZ(lr,    kc, 64, 7));
    bfrag bv1 = *(const bfrag*)(vT_s[w] + SWZ(16+lr, kc, 64, 7));
    o[0][0]=MFMA(pa0,bv0,o[0][0]); o[0][1]=MFMA(pa0,bv1,o[0][1]);
    o[1][0]=MFMA(pa1,bv0,o[1][0]); o[1][1]=MFMA(pa1,bv1,o[1][1]);
  }
  #pragma unroll
  for (int mt=0; mt<2; mt++)
    #pragma unroll
    for (int nt=0; nt<2; nt++)
      #pragma unroll
      for (int r=0; r<4; r++){
        int a = mt*16 + ko*4 + r;
        attB[((long)b*32 + a)*256 + h*32 + nt*16 + lr] = (short)f2bf(o[mt][nt][r]*rsi[mt][r]);
      }
}

// ---------------- K3: GRU cell — 128 rows/block, all 768 gate cols ----------------
// 16 ping-pong sub-phases: p = jblk*2 + part (part 0 = gi/wih, 1 = gh/whh)
__global__ __launch_bounds__(512) void k3_gru(const short* __restrict__ attB,
    const float* __restrict__ h0f, const short* __restrict__ wih, const short* __restrict__ whh,
    const float* __restrict__ b_ih, const float* __restrict__ b_hh,
    const void* __restrict__ scen, float* __restrict__ hout, const int* __restrict__ flagp){
  __shared__ __align__(16) short w_s[2][24576];   // 2 x 48 KB (3 slabs of 32x256)
  int t = threadIdx.x;
  long R0 = (long)blockIdx.x * 128;
  int lane = t&63, w = t>>6, lr = lane&15, ko = lane>>4;
  int mflag = *flagp;
  long abase = (R0 + w*16 + lr) * 256L;
  // A-frags for the whole K range, loaded once
  bfrag a_att[8], a_h0[8];
  #pragma unroll
  for (int ks=0; ks<8; ks++){
    a_att[ks] = *(const bfrag*)(attB + abase + ks*32 + ko*8);
    const float* hp = h0f + abase + ks*32 + ko*8;
    float4 f0 = *(const float4*)hp; float4 f1 = *(const float4*)(hp+4);
    bfrag v8;
    v8[0]=(short)f2bf(f0.x); v8[1]=(short)f2bf(f0.y); v8[2]=(short)f2bf(f0.z); v8[3]=(short)f2bf(f0.w);
    v8[4]=(short)f2bf(f1.x); v8[5]=(short)f2bf(f1.y); v8[6]=(short)f2bf(f1.z); v8[7]=(short)f2bf(f1.w);
    a_h0[ks] = v8;
  }
  auto STAGE = [&](int p){
    int jb = p>>1, part = p&1;
    const short* base = part ? whh : wih;
    short* dst = w_s[p&1];
    #pragma unroll
    for (int i=0;i<6;i++){
      int c = t + i*512; int slab = c>>10; int cm = c&1023; int row = cm>>5; int cc = (cm&31)*8;
      *(bfrag*)(dst + slab*8192 + SWZ(row, cc, 256, 7)) =
          *(const bfrag*)(base + ((long)slab*256 + jb*32 + row)*256 + cc);
    }
  };
  ffrag acc[6][2];
  STAGE(0);
  __syncthreads();
  for (int p=0; p<16; p++){
    int part = p&1, jb = p>>1;
    if (p < 15) STAGE(p+1);
    const short* wc = w_s[p&1];
    #pragma unroll
    for (int g=0; g<3; g++)
      #pragma unroll
      for (int nt=0; nt<2; nt++) acc[part*3+g][nt] = fzero();
    #pragma unroll
    for (int ks=0; ks<8; ks++){
      int kc = ks*32 + ko*8;
      bfrag a = part ? a_h0[ks] : a_att[ks];
      #pragma unroll
      for (int g=0; g<3; g++){
        #pragma unroll
        for (int nt=0; nt<2; nt++){
          bfrag bb = *(const bfrag*)(wc + g*8192 + SWZ(nt*16+lr, kc, 256, 7));
          acc[part*3+g][nt] = MFMA(a, bb, acc[part*3+g][nt]);
        }
      }
    }
    if (part == 1){   // gates + h for cols jb*32 .. jb*32+31
      int j0 = jb*32;
      #pragma unroll
      for (int nt=0; nt<2; nt++){
        int j = j0 + nt*16 + lr;
        float bir = b_ih[j],     bhr = b_hh[j];
        float biz = b_ih[256+j], bhz = b_hh[256+j];
        float bin = b_ih[512+j], bhn = b_hh[512+j];
        #pragma unroll
        for (int r=0;r<4;r++){
          long row = R0 + w*16 + ko*4 + r;
          float ir = acc[0][nt][r], iz = acc[1][nt][r], inn = acc[2][nt][r];
          float hr = acc[3][nt][r], hz = acc[4][nt][r], hn = acc[5][nt][r];
          float rr = 1.f/(1.f + __expf(-(ir + hr + bir + bhr)));
          float zz = 1.f/(1.f + __expf(-(iz + hz + biz + bhz)));
          float ag = inn + bin + rr*(hn + bhn);
          float nn = 2.f/(1.f + __expf(-2.f*ag)) - 1.f;   // tanh
          float h0v = h0f[row*256 + j];
          float hv = (1.f - zz)*nn + zz*h0v;
          if (getmask(scen, row, mflag)) hv = 0.f;
          hout[row*256 + j] = hv;
        }
      }
    }
    __syncthreads();
  }
}

// ---------------- K4: q_out = h @ out_w^T + out_b (masked) ----------------
__global__ __launch_bounds__(512) void k4_out(const float* __restrict__ hout,
    const short* __restrict__ ow, const float* __restrict__ out_b,
    const void* __restrict__ scen, float* __restrict__ qout, const int* __restrict__ flagp){
  __shared__ __align__(16) short ow_s[32*256];
  int t = threadIdx.x; long R0 = (long)blockIdx.x * 256;
  int mflag = *flagp;
  for (int i=0;i<2;i++){
    int c = t + i*512; int row = c >> 5; int cc = (c & 31)*8;
    *(bfrag*)(ow_s + SWZ(row, cc, 256, 7)) = *(const bfrag*)(ow + row*256 + cc);
  }
  __syncthreads();
  int lane = t&63, w = t>>6, lr = lane&15, ko = lane>>4;
  ffrag acc[2][2];
  #pragma unroll
  for (int a=0;a<2;a++) for (int bq=0;bq<2;bq++) acc[a][bq]=fzero();
  for (int ks=0; ks<8; ks++){
    int kc = ks*32 + ko*8;
    #pragma unroll
    for (int mi=0; mi<2; mi++){
      long row = R0 + (w*2+mi)*16 + lr;
      const float* hp = hout + row*256 + kc;
      float4 f0 = *(const float4*)hp; float4 f1 = *(const float4*)(hp+4);
      bfrag a;
      a[0]=(short)f2bf(f0.x); a[1]=(short)f2bf(f0.y); a[2]=(short)f2bf(f0.z); a[3]=(short)f2bf(f0.w);
      a[4]=(short)f2bf(f1.x); a[5]=(short)f2bf(f1.y); a[6]=(short)f2bf(f1.z); a[7]=(short)f2bf(f1.w);
      #pragma unroll
      for (int nt=0; nt<2; nt++){
        bfrag bb = *(const bfrag*)(ow_s + SWZ(nt*16+lr, kc, 256, 7));
        acc[mi][nt] = MFMA(a, bb, acc[mi][nt]);
      }
    }
  }
  #pragma unroll
  for (int mi=0;mi<2;mi++)
    #pragma unroll
    for (int nt=0;nt<2;nt++){
      int col = nt*16 + lr;
      float ob = out_b[col];
      #pragma unroll
      for (int r=0;r<4;r++){
        long row = R0 + (w*2+mi)*16 + ko*4 + r;
        float qv = acc[mi][nt][r] + ob;
        if (getmask(scen, row, mflag)) qv = 0.f;
        qout[row*32 + col] = qv;
      }
    }
}

extern "C" void kernel_launch(void* const* d_in, const int* in_sizes, int n_in,
                              void* d_out, int out_size, void* d_ws, size_t ws_size,
                              hipStream_t stream){
  const float* inputs = (const float*)d_in[0];
  const float* hidden = (const float*)d_in[1];
  const float* fc1_w  = (const float*)d_in[2];
  const float* fc1_b  = (const float*)d_in[3];
  const float* q_w    = (const float*)d_in[4];
  const float* q_b    = (const float*)d_in[5];
  const float* k_w    = (const float*)d_in[6];
  const float* k_b    = (const float*)d_in[7];
  const float* v_w    = (const float*)d_in[8];
  const float* v_b    = (const float*)d_in[9];
  const float* w_ih   = (const float*)d_in[10];
  const float* w_hh   = (const float*)d_in[11];
  const float* b_ih   = (const float*)d_in[12];
  const float* b_hh   = (const float*)d_in[13];
  const float* out_w  = (const float*)d_in[14];
  const float* out_b  = (const float*)d_in[15];
  const void* obsm    = d_in[16];
  const void* scen    = d_in[17];
  (void)in_sizes; (void)n_in; (void)out_size;
  if ((long)ws_size < WS_NEED_BYTES) return;
  short* ws = (short*)d_ws;
  const int* flagp = (const int*)d_ws;
  float* qout = (float*)d_out;
  float* hout = qout + 4194304;
  // chunk scratch: k/v chunks (2048 batches) borrow the dead hout region
  short* kCs = (short*)hout;             // 2048*64*256 shorts = 67 MB
  short* vCs = kCs + 33554432L;          // 67 MB (fills hout region exactly)
  short* qF  = ws + OFF_QFULL;           // full-batch q (bf16)
  short* attB = ws + OFF_ATTB;

  hipLaunchKernelGGL(k0_prep, dim3(1024), dim3(256), 0, stream,
      fc1_w, q_w, k_w, v_w, w_ih, w_hh, out_w, obsm, ws);
  for (int c=0; c<2; c++){
    hipLaunchKernelGGL(k1_fqkv, dim3(1024), dim3(512), 0, stream,
        inputs, ws + OFF_FC1, fc1_b, ws + OFF_QW, ws + OFF_KW, ws + OFF_VW,
        q_b, k_b, v_b, qF, kCs, vCs, c);
    hipLaunchKernelGGL(k2_attn, dim3(2048), dim3(512), 0, stream,
        qF, kCs, vCs, obsm, attB, flagp, c);
  }
  hipLaunchKernelGGL(k3_gru, dim3(1024), dim3(512), 0, stream,
      attB, hidden, ws + OFF_WIH, ws + OFF_WHH, b_ih, b_hh, scen, hout, flagp);
  hipLaunchKernelGGL(k4_out, dim3(512), dim3(512), 0, stream,
      hout, ws + OFF_OW, out_b, scen, qout, flagp);
}

// Round 4
// 717.976 us; speedup vs baseline: 1.1486x; 1.1486x over previous
//
#include <hip/hip_runtime.h>

// ATTNRNNAgent: B=4096, N=64, E=128, A=32, nh=8, e=32, HID=256, ATT=256, N_ACT=32
// K0 (weights->bf16, A2 h0-half, mask dtype) -> 4x( k1_fqkv, k2_attn ) -> k3_gru -> k4_out
// k3 key idea: A2 = [att | h0] (K=512) so r,z gates are single GEMMs; 4:1 MFMA:ds_read reuse.
// All GEMMs via v_mfma_f32_16x16x32_bf16
//   A-frag: row=lane&15, k=(lane>>4)*8+i ; B-frag: col=lane&15 same k
//   D-frag: col=lane&15, row=(lane>>4)*4+r

using bfrag = __attribute__((ext_vector_type(8))) short;   // 8 bf16
using ffrag = __attribute__((ext_vector_type(4))) float;   // 4 f32 acc

#define MFMA(a,b,c) __builtin_amdgcn_mfma_f32_16x16x32_bf16((a),(b),(c),0,0,0)
// XOR swizzle for row-major bf16 LDS tiles (16B granular)
#define SWZ(row,col,S,xm) ((row)*(S) + ((((col)&~7) ^ (((row)&(xm))<<3)) | ((col)&7)))

// ws layout (in shorts). A2 first (131072 x 512), then bf16 weights, then flag.
#define OFF_A2   0L
#define OFF_FC1  67108864L
#define OFF_QW   67141632L
#define OFF_KW   67207168L
#define OFF_VW   67272704L
#define OFF_WIH  67338240L
#define OFF_WHH  67534848L
#define OFF_OW   67731456L
#define OFF_FLAG 67739648L
#define WS_NEED_BYTES 135479552L

__device__ inline unsigned short f2bf(float x){
  union { float f; unsigned u; } v; v.f = x;
  unsigned r = v.u + 0x7fffu + ((v.u >> 16) & 1u);   // RNE
  return (unsigned short)(r >> 16);
}
__device__ inline float bf2f(short b){
  union { unsigned u; float f; } v; v.u = ((unsigned)(unsigned short)b) << 16;
  return v.f;
}
__device__ inline bool getmask(const void* p, long i, int byteflag){
  return byteflag ? (((const unsigned char*)p)[i] != 0)
                  : (((const int*)p)[i] != 0);
}
__device__ inline ffrag fzero(){ ffrag z; z[0]=0.f; z[1]=0.f; z[2]=0.f; z[3]=0.f; return z; }

// ---------------- K0: weights -> bf16, A2 h0-half, detect mask dtype ----------------
__global__ void k0_prep(const float* __restrict__ fc1, const float* __restrict__ qw,
    const float* __restrict__ kw, const float* __restrict__ vw, const float* __restrict__ wih,
    const float* __restrict__ whh, const float* __restrict__ ow, const float* __restrict__ h0,
    const void* __restrict__ obsm, short* __restrict__ ws){
  long tid = (long)blockIdx.x*blockDim.x + threadIdx.x;
  long n = (long)gridDim.x*blockDim.x;
  if (tid == 0){
    const int* mi = (const int*)obsm;
    int f = 0;
    for (int i=0;i<256;i++){ if ((unsigned)mi[i] > 1u){ f = 1; break; } }
    ((int*)(ws + OFF_FLAG))[0] = f;
  }
  for (long i=tid; i<32768; i+=n) ws[OFF_FC1+i] = (short)f2bf(fc1[i]);
  for (long i=tid; i<65536; i+=n){
    ws[OFF_QW+i] = (short)f2bf(qw[i]);
    ws[OFF_KW+i] = (short)f2bf(kw[i]);
    ws[OFF_VW+i] = (short)f2bf(vw[i]);
  }
  for (long i=tid; i<196608; i+=n){
    ws[OFF_WIH+i] = (short)f2bf(wih[i]);
    ws[OFF_WHH+i] = (short)f2bf(whh[i]);
  }
  for (long i=tid; i<8192; i+=n) ws[OFF_OW+i] = (short)f2bf(ow[i]);
  // A2 h0 half: A2[row*512 + 256 + j] = bf16(h0[row*256 + j])
  for (long i=tid; i<33554432L; i+=n){
    long row = i >> 8; int j = (int)(i & 255);
    ws[OFF_A2 + row*512 + 256 + j] = (short)f2bf(h0[i]);
  }
}

// ---------------- K1: fused fc1 + QKV projection (per 65536-row chunk) ----------------
__global__ __launch_bounds__(512) void k1_fqkv(const float* __restrict__ inp,
    const short* __restrict__ fc1B, const float* __restrict__ fc1_b,
    const short* __restrict__ wq, const short* __restrict__ wk, const short* __restrict__ wv,
    const float* __restrict__ qb, const float* __restrict__ kb, const float* __restrict__ vb,
    short* __restrict__ qC, short* __restrict__ kC, short* __restrict__ vC, int chunkB){
  __shared__ __align__(16) short smem[65536];   // 128 KB
  short* a_s  = smem;            // phase1 A: 128x128 (32 KB)
  short* fw_s = smem + 16384;    // phase1 W: 256x128 (64 KB)
  short* x_s  = smem;            // phase2 X: 128x256 (64 KB)
  int t = threadIdx.x;
  long R0 = (long)blockIdx.x * 128;            // chunk-local row base
  long grow0 = (long)chunkB*65536 + R0;        // global input row base
  int lane = t&63, w = t>>6, lr = lane&15, ko = lane>>4;
  for (int i=0;i<4;i++){
    int c = t + i*512; int row = c>>4; int cc = (c&15)*8;
    const float* src = inp + (grow0 + row)*128 + cc;
    float4 f0 = *(const float4*)src; float4 f1 = *(const float4*)(src+4);
    bfrag v8;
    v8[0]=(short)f2bf(f0.x); v8[1]=(short)f2bf(f0.y); v8[2]=(short)f2bf(f0.z); v8[3]=(short)f2bf(f0.w);
    v8[4]=(short)f2bf(f1.x); v8[5]=(short)f2bf(f1.y); v8[6]=(short)f2bf(f1.z); v8[7]=(short)f2bf(f1.w);
    *(bfrag*)(a_s + SWZ(row, cc, 128, 7)) = v8;
  }
  for (int i=0;i<8;i++){
    int c = t + i*512; int row = c>>4; int cc = (c&15)*8;
    *(bfrag*)(fw_s + SWZ(row, cc, 128, 7)) = *(const bfrag*)(fc1B + row*128 + cc);
  }
  __syncthreads();
  ffrag acc1[16];
  #pragma unroll
  for (int i=0;i<16;i++) acc1[i]=fzero();
  for (int ks=0; ks<4; ks++){
    int kc = ks*32 + ko*8;
    bfrag a = *(const bfrag*)(a_s + SWZ(w*16+lr, kc, 128, 7));
    #pragma unroll
    for (int nt=0; nt<16; nt++){
      bfrag bb = *(const bfrag*)(fw_s + SWZ(nt*16+lr, kc, 128, 7));
      acc1[nt] = MFMA(a, bb, acc1[nt]);
    }
  }
  __syncthreads();   // all phase1 LDS reads complete -> reuse smem
  #pragma unroll
  for (int nt=0; nt<16; nt++){
    float bias = fc1_b[nt*16+lr];
    #pragma unroll
    for (int r=0;r<4;r++){
      int row = w*16 + ko*4 + r;
      float v = acc1[nt][r] + bias; v = v>0.f?v:0.f;
      x_s[SWZ(row, nt*16+lr, 256, 7)] = (short)f2bf(v);
    }
  }
  bfrag a_r[8];
  #pragma unroll
  for (int ks=0; ks<8; ks++)
    a_r[ks] = *(const bfrag*)(x_s + SWZ(w*16+lr, ks*32+ko*8, 256, 7));
  auto STAGE2 = [&](int s){
    int kind = s>>2; int rb = (s&3)*64;
    const short* wsrc = (kind==0?wq:(kind==1?wk:wv)) + (long)rb*256;
    short* dst = smem + 32768 + (s&1)*16384;
    #pragma unroll
    for (int i=0;i<4;i++){
      int c = t + i*512; int row = c>>5; int cc = (c&31)*8;
      *(bfrag*)(dst + SWZ(row, cc, 256, 7)) = *(const bfrag*)(wsrc + (long)row*256 + cc);
    }
  };
  STAGE2(0);
  __syncthreads();
  for (int s=0; s<12; s++){
    if (s < 11) STAGE2(s+1);
    const short* wcur = smem + 32768 + (s&1)*16384;
    ffrag acc2[4];
    #pragma unroll
    for (int i=0;i<4;i++) acc2[i]=fzero();
    #pragma unroll
    for (int ks=0; ks<8; ks++){
      int kc = ks*32 + ko*8;
      #pragma unroll
      for (int nt=0; nt<4; nt++){
        bfrag bb = *(const bfrag*)(wcur + SWZ(nt*16+lr, kc, 256, 7));
        acc2[nt] = MFMA(a_r[ks], bb, acc2[nt]);
      }
    }
    int kind = s>>2; int rb = (s&3)*64;
    const float* bsrc = (kind==0?qb:(kind==1?kb:vb));
    #pragma unroll
    for (int nt=0; nt<4; nt++){
      int colk = rb + nt*16 + lr;
      float bias = bsrc[colk];
      #pragma unroll
      for (int r=0;r<4;r++){
        int row = w*16 + ko*4 + r;
        long rl = R0 + row;
        float v = acc2[nt][r] + bias;
        if (kind==0){
          if ((row&32)==0){                       // q: only agent rows n<32
            long qrow = ((rl>>6)<<5) + (row&31);
            qC[qrow*256 + colk] = (short)f2bf(v);
          }
        } else if (kind==1){
          kC[rl*256 + colk] = (short)f2bf(v);
        } else {
          v = v>0.f?v:0.f;
          vC[rl*256 + colk] = (short)f2bf(v);
        }
      }
    }
    __syncthreads();
  }
}

// ---------------- K2: attention, one wave per (b,head); att -> A2 cols 0..255 ----------------
__global__ __launch_bounds__(512,4) void k2_attn(const short* __restrict__ qC,
    const short* __restrict__ kC, const short* __restrict__ vC,
    const void* __restrict__ obsm, short* __restrict__ A2,
    const int* __restrict__ flagp, int chunkB){
  __shared__ __align__(16) short vT_s[8][2048];   // per-wave v^T [e=32][n=64]
  __shared__ __align__(16) short p_s[8][2048];    // per-wave p   [a=32][n=64]
  __shared__ unsigned char m_s[2048];             // obs_mask rows 0..31
  int t = threadIdx.x, bl = blockIdx.x;
  long b = (long)chunkB*1024 + bl;
  int lane = t&63, w = t>>6, lr = lane&15, ko = lane>>4;
  int mflag = *flagp;
  if (mflag){
    uchar4 mv = *(const uchar4*)((const unsigned char*)obsm + b*4096 + t*4);
    m_s[t*4]=mv.x; m_s[t*4+1]=mv.y; m_s[t*4+2]=mv.z; m_s[t*4+3]=mv.w;
  } else {
    int4 mv = *(const int4*)((const int*)obsm + b*4096 + t*4);
    m_s[t*4]  =(unsigned char)(mv.x!=0); m_s[t*4+1]=(unsigned char)(mv.y!=0);
    m_s[t*4+2]=(unsigned char)(mv.z!=0); m_s[t*4+3]=(unsigned char)(mv.w!=0);
  }
  const int h = w;
  const short* qh = qC + ((long)bl*32)*256 + h*32 + ko*8;
  bfrag a_q[2];
  #pragma unroll
  for (int mt=0; mt<2; mt++) a_q[mt] = *(const bfrag*)(qh + (mt*16+lr)*256);
  const short* kh = kC + ((long)bl*64)*256 + h*32 + ko*8;
  bfrag b_k[4];
  #pragma unroll
  for (int nt=0; nt<4; nt++) b_k[nt] = *(const bfrag*)(kh + (nt*16+lr)*256);
  #pragma unroll
  for (int i=0;i<4;i++){
    int n = i*16 + (lane>>2); int e0 = (lane&3)*8;
    bfrag vv = *(const bfrag*)(vC + ((long)bl*64 + n)*256 + h*32 + e0);
    #pragma unroll
    for (int j=0;j<8;j++) vT_s[w][SWZ(e0+j, n, 64, 7)] = vv[j];
  }
  ffrag sc[2][4];
  #pragma unroll
  for (int mt=0; mt<2; mt++)
    #pragma unroll
    for (int nt=0; nt<4; nt++) sc[mt][nt] = MFMA(a_q[mt], b_k[nt], fzero());
  __syncthreads();   // m_s ready (vT/p are wave-private)
  const float scale = 0.17677669529663687f;   // 1/sqrt(32)
  float rsi[2][4];
  #pragma unroll
  for (int mt=0; mt<2; mt++){
    #pragma unroll
    for (int r=0; r<4; r++){
      int arow = mt*16 + ko*4 + r;
      float sv[4]; int mk[4];
      #pragma unroll
      for (int nt=0; nt<4; nt++){
        mk[nt] = m_s[arow*64 + nt*16 + lr];
        sv[nt] = sc[mt][nt][r] * scale;
      }
      float mx = -3.0e38f;
      #pragma unroll
      for (int nt=0; nt<4; nt++) if (!mk[nt]) mx = fmaxf(mx, sv[nt]);
      for (int d=1; d<16; d<<=1) mx = fmaxf(mx, __shfl_xor(mx, d));
      float sum = 0.f;
      #pragma unroll
      for (int nt=0; nt<4; nt++){
        float p = mk[nt] ? 0.f : __expf(sv[nt]-mx);
        sv[nt] = p; sum += p;
      }
      for (int d=1; d<16; d<<=1) sum += __shfl_xor(sum, d);
      rsi[mt][r] = sum > 0.f ? 1.f/sum : 0.f;   // all-masked row -> 0
      #pragma unroll
      for (int nt=0; nt<4; nt++)
        p_s[w][SWZ(arow, nt*16+lr, 64, 7)] = (short)f2bf(sv[nt]);
    }
  }
  ffrag o[2][2];
  #pragma unroll
  for (int mt=0;mt<2;mt++)
    #pragma unroll
    for (int nt=0;nt<2;nt++) o[mt][nt]=fzero();
  #pragma unroll
  for (int kk=0; kk<2; kk++){
    int kc = kk*32 + ko*8;
    bfrag pa0 = *(const bfrag*)(p_s[w]  + SWZ(lr,    kc, 64, 7));
    bfrag pa1 = *(const bfrag*)(p_s[w]  + SWZ(16+lr, kc, 64, 7));
    bfrag bv0 = *(const bfrag*)(vT_s[w] + SWZ(lr,    kc, 64, 7));
    bfrag bv1 = *(const bfrag*)(vT_s[w] + SWZ(16+lr, kc, 64, 7));
    o[0][0]=MFMA(pa0,bv0,o[0][0]); o[0][1]=MFMA(pa0,bv1,o[0][1]);
    o[1][0]=MFMA(pa1,bv0,o[1][0]); o[1][1]=MFMA(pa1,bv1,o[1][1]);
  }
  #pragma unroll
  for (int mt=0; mt<2; mt++)
    #pragma unroll
    for (int nt=0; nt<2; nt++)
      #pragma unroll
      for (int r=0; r<4; r++){
        int a = mt*16 + ko*4 + r;
        A2[((long)b*32 + a)*512 + h*32 + nt*16 + lr] = (short)f2bf(o[mt][nt][r]*rsi[mt][r]);
      }
}

// ---------------- K3: GRU via A2=[att|h0] K=512, 4:1 MFMA:ds reuse ----------------
// block = 512 rows x 32 h-cols (jb). grid = jb*256 + rowgroup (same-rows same-XCD).
// wave = 64 rows (Mt=4). B from once-staged 96KB LDS; A streamed from A2 (L2-shared).
__global__ __launch_bounds__(512) void k3_gru(const short* __restrict__ A2,
    const short* __restrict__ wihB, const short* __restrict__ whhB,
    const float* __restrict__ b_ih, const float* __restrict__ b_hh,
    const void* __restrict__ scen, float* __restrict__ hout, const int* __restrict__ flagp){
  __shared__ __align__(16) short w_s[49152];   // 6 slabs of 32x256 (16KB each), 96 KB
  int t = threadIdx.x, bid = blockIdx.x;
  int jb = bid >> 8, rg = bid & 255;
  long R0 = (long)rg * 512;
  int mflag = *flagp;
  // stage 6 slabs: slab = g*2+p : rows (g*256 + jb*32 ..+31) of (p? whh : wih)
  for (int i=0;i<12;i++){
    int c = t + i*512; int slab = c>>10; int cm = c&1023; int row = cm>>5; int cc = (cm&31)*8;
    const short* src = (slab&1 ? whhB : wihB) + ((long)((slab>>1)*256 + jb*32 + row))*256 + cc;
    *(bfrag*)(w_s + slab*8192 + SWZ(row, cc, 256, 7)) = *(const bfrag*)src;
  }
  __syncthreads();
  int lane = t&63, w = t>>6, lr = lane&15, ko = lane>>4;
  long rowbase = R0 + (long)w*64;
  const short* Abase = A2 + (rowbase + lr)*512 + ko*8;
  ffrag aR[2][4], aZ[2][4], aI[2][4], aN[2][4];
  #pragma unroll
  for (int nt=0;nt<2;nt++)
    #pragma unroll
    for (int mt=0;mt<4;mt++){ aR[nt][mt]=fzero(); aZ[nt][mt]=fzero(); aI[nt][mt]=fzero(); aN[nt][mt]=fzero(); }
  bfrag aCur[4], aNxt[4];
  #pragma unroll
  for (int mt=0;mt<4;mt++) aCur[mt] = *(const bfrag*)(Abase + (long)mt*8192);
  #pragma unroll
  for (int ks=0; ks<16; ks++){
    if (ks < 15){
      #pragma unroll
      for (int mt=0;mt<4;mt++) aNxt[mt] = *(const bfrag*)(Abase + (long)mt*8192 + (ks+1)*32);
    }
    int kc = (ks&7)*32 + ko*8;
    int p = ks>>3;
    #pragma unroll
    for (int nt=0; nt<2; nt++){
      bfrag bR = *(const bfrag*)(w_s + (0+p)*8192 + SWZ(nt*16+lr, kc, 256, 7));
      bfrag bZ = *(const bfrag*)(w_s + (2+p)*8192 + SWZ(nt*16+lr, kc, 256, 7));
      bfrag bX = *(const bfrag*)(w_s + (4+p)*8192 + SWZ(nt*16+lr, kc, 256, 7));
      #pragma unroll
      for (int mt=0; mt<4; mt++){
        aR[nt][mt] = MFMA(aCur[mt], bR, aR[nt][mt]);
        aZ[nt][mt] = MFMA(aCur[mt], bZ, aZ[nt][mt]);
        if (p==0) aI[nt][mt] = MFMA(aCur[mt], bX, aI[nt][mt]);
        else      aN[nt][mt] = MFMA(aCur[mt], bX, aN[nt][mt]);
      }
    }
    #pragma unroll
    for (int mt=0;mt<4;mt++) aCur[mt] = aNxt[mt];
  }
  // epilogue: gates + h
  #pragma unroll
  for (int nt=0; nt<2; nt++){
    int j = jb*32 + nt*16 + lr;
    float bir = b_ih[j],     bhr = b_hh[j];
    float biz = b_ih[256+j], bhz = b_hh[256+j];
    float bin = b_ih[512+j], bhn = b_hh[512+j];
    #pragma unroll
    for (int mt=0; mt<4; mt++){
      #pragma unroll
      for (int rr=0; rr<4; rr++){
        long row = rowbase + mt*16 + ko*4 + rr;
        float rg_ = 1.f/(1.f + __expf(-(aR[nt][mt][rr] + bir + bhr)));
        float zg  = 1.f/(1.f + __expf(-(aZ[nt][mt][rr] + biz + bhz)));
        float ag  = aI[nt][mt][rr] + bin + rg_*(aN[nt][mt][rr] + bhn);
        float ng  = 2.f/(1.f + __expf(-2.f*ag)) - 1.f;   // tanh
        float h0v = bf2f(A2[row*512 + 256 + j]);
        float hv = (1.f - zg)*ng + zg*h0v;
        if (getmask(scen, row, mflag)) hv = 0.f;
        hout[row*256 + j] = hv;
      }
    }
  }
}

// ---------------- K4: q_out = h @ out_w^T + out_b (masked) ----------------
__global__ __launch_bounds__(512) void k4_out(const float* __restrict__ hout,
    const short* __restrict__ ow, const float* __restrict__ out_b,
    const void* __restrict__ scen, float* __restrict__ qout, const int* __restrict__ flagp){
  __shared__ __align__(16) short ow_s[32*256];
  int t = threadIdx.x; long R0 = (long)blockIdx.x * 256;
  int mflag = *flagp;
  for (int i=0;i<2;i++){
    int c = t + i*512; int row = c >> 5; int cc = (c & 31)*8;
    *(bfrag*)(ow_s + SWZ(row, cc, 256, 7)) = *(const bfrag*)(ow + row*256 + cc);
  }
  __syncthreads();
  int lane = t&63, w = t>>6, lr = lane&15, ko = lane>>4;
  ffrag acc[2][2];
  #pragma unroll
  for (int a=0;a<2;a++) for (int bq=0;bq<2;bq++) acc[a][bq]=fzero();
  for (int ks=0; ks<8; ks++){
    int kc = ks*32 + ko*8;
    #pragma unroll
    for (int mi=0; mi<2; mi++){
      long row = R0 + (w*2+mi)*16 + lr;
      const float* hp = hout + row*256 + kc;
      float4 f0 = *(const float4*)hp; float4 f1 = *(const float4*)(hp+4);
      bfrag a;
      a[0]=(short)f2bf(f0.x); a[1]=(short)f2bf(f0.y); a[2]=(short)f2bf(f0.z); a[3]=(short)f2bf(f0.w);
      a[4]=(short)f2bf(f1.x); a[5]=(short)f2bf(f1.y); a[6]=(short)f2bf(f1.z); a[7]=(short)f2bf(f1.w);
      #pragma unroll
      for (int nt=0; nt<2; nt++){
        bfrag bb = *(const bfrag*)(ow_s + SWZ(nt*16+lr, kc, 256, 7));
        acc[mi][nt] = MFMA(a, bb, acc[mi][nt]);
      }
    }
  }
  #pragma unroll
  for (int mi=0;mi<2;mi++)
    #pragma unroll
    for (int nt=0;nt<2;nt++){
      int col = nt*16 + lr;
      float ob = out_b[col];
      #pragma unroll
      for (int r=0;r<4;r++){
        long row = R0 + (w*2+mi)*16 + ko*4 + r;
        float qv = acc[mi][nt][r] + ob;
        if (getmask(scen, row, mflag)) qv = 0.f;
        qout[row*32 + col] = qv;
      }
    }
}

extern "C" void kernel_launch(void* const* d_in, const int* in_sizes, int n_in,
                              void* d_out, int out_size, void* d_ws, size_t ws_size,
                              hipStream_t stream){
  const float* inputs = (const float*)d_in[0];
  const float* hidden = (const float*)d_in[1];
  const float* fc1_w  = (const float*)d_in[2];
  const float* fc1_b  = (const float*)d_in[3];
  const float* q_w    = (const float*)d_in[4];
  const float* q_b    = (const float*)d_in[5];
  const float* k_w    = (const float*)d_in[6];
  const float* k_b    = (const float*)d_in[7];
  const float* v_w    = (const float*)d_in[8];
  const float* v_b    = (const float*)d_in[9];
  const float* w_ih   = (const float*)d_in[10];
  const float* w_hh   = (const float*)d_in[11];
  const float* b_ih   = (const float*)d_in[12];
  const float* b_hh   = (const float*)d_in[13];
  const float* out_w  = (const float*)d_in[14];
  const float* out_b  = (const float*)d_in[15];
  const void* obsm    = d_in[16];
  const void* scen    = d_in[17];
  (void)in_sizes; (void)n_in; (void)out_size;
  if ((long)ws_size < WS_NEED_BYTES) return;
  short* ws = (short*)d_ws;
  const int* flagp = (const int*)(ws + OFF_FLAG);
  float* qout = (float*)d_out;
  float* hout = qout + 4194304;
  // per-chunk scratch in dead d_out regions (1024 batches/chunk):
  short* qCs = (short*)qout;             // 1024*32*256 shorts = qout region exactly
  short* kCs = (short*)hout;             // 1024*64*256 shorts
  short* vCs = kCs + 16777216L;          // 1024*64*256 shorts
  short* A2  = ws + OFF_A2;

  hipLaunchKernelGGL(k0_prep, dim3(2048), dim3(256), 0, stream,
      fc1_w, q_w, k_w, v_w, w_ih, w_hh, out_w, hidden, obsm, ws);
  for (int c=0; c<4; c++){
    hipLaunchKernelGGL(k1_fqkv, dim3(512), dim3(512), 0, stream,
        inputs, ws + OFF_FC1, fc1_b, ws + OFF_QW, ws + OFF_KW, ws + OFF_VW,
        q_b, k_b, v_b, qCs, kCs, vCs, c);
    hipLaunchKernelGGL(k2_attn, dim3(1024), dim3(512), 0, stream,
        qCs, kCs, vCs, obsm, A2, flagp, c);
  }
  hipLaunchKernelGGL(k3_gru, dim3(2048), dim3(512), 0, stream,
      A2, ws + OFF_WIH, ws + OFF_WHH, b_ih, b_hh, scen, hout, flagp);
  hipLaunchKernelGGL(k4_out, dim3(512), dim3(512), 0, stream,
      hout, ws + OFF_OW, out_b, scen, qout, flagp);
}